// Round 1
// baseline (111.513 us; speedup 1.0000x reference)
//
#include <hip/hip_runtime.h>

#define N_ATOMS 250000
#define NR 8

__global__ __launch_bounds__(256) void moment_contr_kernel(
    const float* __restrict__ m1,   // [A, 8, 3]
    const float* __restrict__ m2,   // [A, 8, 3, 3]
    float* __restrict__ out)        // flat: out[p*2000000 + t*250000 + a]
{
    const int a = blockIdx.x * blockDim.x + threadIdx.x;
    if (a >= N_ATOMS) return;

    // ---- load m1[a]: 24 floats via 6x float4 (96 B contiguous per lane) ----
    float m1v[24];
    {
        const float4* p = reinterpret_cast<const float4*>(m1 + (size_t)a * 24);
        #pragma unroll
        for (int k = 0; k < 6; ++k) {
            float4 v = p[k];
            m1v[4*k+0] = v.x; m1v[4*k+1] = v.y;
            m1v[4*k+2] = v.z; m1v[4*k+3] = v.w;
        }
    }

    // ---- load m2[a]: 72 floats via 18x float4 (288 B contiguous per lane) ----
    float m2v[72];
    {
        const float4* p = reinterpret_cast<const float4*>(m2 + (size_t)a * 72);
        #pragma unroll
        for (int k = 0; k < 18; ++k) {
            float4 v = p[k];
            m2v[4*k+0] = v.x; m2v[4*k+1] = v.y;
            m2v[4*k+2] = v.z; m2v[4*k+3] = v.w;
        }
    }

    float* outa = out + a;

    // t-loop rolled (keeps code size / I-cache sane); everything inside unrolled
    // with compile-time register indexing.
    for (int t = 0; t < NR; ++t) {
        // B[s][i] = sum_j m1[s,j] * m2[t,i,j]   (24 regs)
        float B[24];
        #pragma unroll
        for (int s = 0; s < NR; ++s) {
            #pragma unroll
            for (int i = 0; i < 3; ++i) {
                B[s*3+i] = m1v[s*3+0] * m2v[t*9 + i*3 + 0]
                         + m1v[s*3+1] * m2v[t*9 + i*3 + 1]
                         + m1v[s*3+2] * m2v[t*9 + i*3 + 2];
            }
        }
        // contr[r,s,t] = sum_i m1[r,i] * B[s,i]; p = r*(r+1)/2 + s matches
        // np.tril_indices(8) order: (0,0),(1,0),(1,1),(2,0),...
        #pragma unroll
        for (int r = 0; r < NR; ++r) {
            #pragma unroll
            for (int s = 0; s <= r; ++s) {
                const int p = r*(r+1)/2 + s;
                float v = m1v[r*3+0] * B[s*3+0]
                        + m1v[r*3+1] * B[s*3+1]
                        + m1v[r*3+2] * B[s*3+2];
                outa[(size_t)p * (NR * N_ATOMS) + (size_t)t * N_ATOMS] = v;
            }
        }
    }
}

extern "C" void kernel_launch(void* const* d_in, const int* in_sizes, int n_in,
                              void* d_out, int out_size, void* d_ws, size_t ws_size,
                              hipStream_t stream) {
    const float* m1 = (const float*)d_in[0];
    const float* m2 = (const float*)d_in[1];
    float* out = (float*)d_out;

    const int block = 256;
    const int grid = (N_ATOMS + block - 1) / block;
    hipLaunchKernelGGL(moment_contr_kernel, dim3(grid), dim3(block), 0, stream,
                       m1, m2, out);
}